// Round 4
// baseline (506.082 us; speedup 1.0000x reference)
//
#include <hip/hip_runtime.h>
#include <hip/hip_bf16.h>

// Problem constants
#define NPTS   3000
#define MPTS   3000
#define KNODES 6000
#define HEADS  4
#define HID    64
#define FDIM   256      // HEADS*HID
#define OUTC   2
#define R2     0.0025f
#define NSLOPE 0.2f
#define MAXNBR 64
#define GRID   512      // 2 blocks/CU (guaranteed by __launch_bounds__(256,2) + 12KB LDS)
#define NROWS  12       // nbr rows per block-group: 6000/12 = 500 groups
#define G2ROWS 12       // gemm2 rows per tile: 500 tiles

// ---------------- workspace layout (floats) ----------------
#define OFF_PX   0
#define OFF_PY   6000
#define OFF_PZ   12000
#define OFF_SQ   18000
#define OFF_ES   24000
#define OFF_ED   48000
#define OFF_A    72000        // x (layer-1 out / gemm2 in), 6000*256
#define OFF_B    1608000      // h (transform out), 6000*256
#define OFF_END  3144000      // floats; int region starts at byte 4*OFF_END

struct KP {
    const float *pos, *pnm, *W1, *as1, *ad1, *b1, *W2, *as2, *ad2, *b2, *fcw, *fcb;
    float *px, *py, *pz, *sq, *es, *ed, *x, *h, *out;
    int *cnt, *idx;
    unsigned *bar;   // [0]=arrival count, [1]=generation (zeroed host-side)
};

// Manual grid barrier. Safe because all GRID blocks are co-resident by
// construction (2 blocks/CU x 256 CUs). Agent-scope atomics + __threadfence
// (buffer_wbl2/inv sc1) give cross-XCD visibility of prior plain stores.
__device__ __forceinline__ void gbar(unsigned* cnt, unsigned* gen) {
    __syncthreads();
    if (threadIdx.x == 0) {
        __threadfence();   // release: flush this CU/XCD's writes device-wide
        unsigned g = __hip_atomic_load(gen, __ATOMIC_RELAXED, __HIP_MEMORY_SCOPE_AGENT);
        unsigned a = __hip_atomic_fetch_add(cnt, 1u, __ATOMIC_ACQ_REL, __HIP_MEMORY_SCOPE_AGENT);
        if (a == GRID - 1) {
            __hip_atomic_store(cnt, 0u, __ATOMIC_RELAXED, __HIP_MEMORY_SCOPE_AGENT);
            __hip_atomic_fetch_add(gen, 1u, __ATOMIC_ACQ_REL, __HIP_MEMORY_SCOPE_AGENT);
        } else {
            while (__hip_atomic_load(gen, __ATOMIC_ACQUIRE, __HIP_MEMORY_SCOPE_AGENT) == g)
                __builtin_amdgcn_s_sleep(1);
        }
        __threadfence();   // acquire: invalidate stale cached lines
    }
    __syncthreads();
}

__global__ __launch_bounds__(256, 2) void k_fused(KP p) {
    __shared__ __align__(16) float sh[3072];   // 12 KB, aliased per phase
    const int t = threadIdx.x;

    // ---------- P1: pts SoA + sq + h1 = pts@W1 + layer-1 scores ----------
    // sq uses exact fp32 ops (no contraction) to match reference mask bitwise.
    for (int i = blockIdx.x; i < KNODES; i += GRID) {
        float x, y, z;
        if (i < NPTS) {
            x = p.pos[i]; y = p.pos[NPTS + i]; z = p.pos[2 * NPTS + i];
        } else {
            int q = i - NPTS;
            x = p.pnm[q]; y = p.pnm[MPTS + q]; z = p.pnm[2 * MPTS + q];
        }
        if (t == 0) {
            p.px[i] = x; p.py[i] = y; p.pz[i] = z;
            p.sq[i] = __fadd_rn(__fadd_rn(__fmul_rn(x, x), __fmul_rn(y, y)),
                                __fmul_rn(z, z));
        }
        float hv = fmaf(x, p.W1[t], fmaf(y, p.W1[FDIM + t], z * p.W1[2 * FDIM + t]));
        p.h[i * FDIM + t] = hv;
        float s = hv * p.as1[t];
        float d = hv * p.ad1[t];
        for (int off = 32; off; off >>= 1) {
            s += __shfl_down(s, off, 64);
            d += __shfl_down(d, off, 64);
        }
        if ((t & 63) == 0) {
            p.es[i * HEADS + (t >> 6)] = s;
            p.ed[i * HEADS + (t >> 6)] = d;
        }
    }
    gbar(p.bar, p.bar + 1);

    // ---------- P2: neighbor lists (gram trick, exact fp32 ops) ----------
    {
        int* s_cnt  = (int*)sh;            // [NROWS]
        int* s_nidx = (int*)sh + 16;       // [NROWS][MAXNBR]
        for (int g = blockIdx.x; g < KNODES / NROWS; g += GRID) {
            int i0 = g * NROWS;
            if (t < NROWS) s_cnt[t] = 0;
            __syncthreads();
            float xi[NROWS], yi[NROWS], zi[NROWS], si[NROWS];
#pragma unroll
            for (int r = 0; r < NROWS; ++r) {
                xi[r] = p.px[i0 + r]; yi[r] = p.py[i0 + r];
                zi[r] = p.pz[i0 + r]; si[r] = p.sq[i0 + r];
            }
            for (int j = t; j < KNODES; j += 256) {
                float xj = p.px[j], yj = p.py[j], zj = p.pz[j], sj = p.sq[j];
#pragma unroll
                for (int r = 0; r < NROWS; ++r) {
                    float dot = __fadd_rn(__fadd_rn(__fmul_rn(xi[r], xj),
                                                    __fmul_rn(yi[r], yj)),
                                          __fmul_rn(zi[r], zj));
                    float d2 = __fsub_rn(__fadd_rn(si[r], sj), __fmul_rn(2.0f, dot));
                    if (d2 < R2) {
                        int pp = atomicAdd(&s_cnt[r], 1);
                        if (pp < MAXNBR) s_nidx[r * MAXNBR + pp] = j;
                    }
                }
            }
            __syncthreads();
            if (t < NROWS) p.cnt[i0 + t] = min(s_cnt[t], MAXNBR);
#pragma unroll
            for (int r = 0; r < NROWS; ++r) {
                int c = min(s_cnt[r], MAXNBR);
                if (t < c) p.idx[(i0 + r) * MAXNBR + t] = s_nidx[r * MAXNBR + t];
            }
            __syncthreads();
        }
    }
    gbar(p.bar, p.bar + 1);

    // ---------- P3: layer-1 softmax-aggregate + bias + relu -> x ----------
    {
        int*   s_idx = (int*)sh;       // [64]
        float* s_e   = sh + 64;        // [256]
        float* s_ed  = sh + 320;       // [4]
        for (int i = blockIdx.x; i < KNODES; i += GRID) {
            int c = p.cnt[i];
            if (t < c) s_idx[t] = p.idx[i * MAXNBR + t];
            if (t < HEADS) s_ed[t] = p.ed[i * HEADS + t];
            __syncthreads();
            if (t < c * HEADS) {
                int jl = t >> 2, hh = t & 3;
                float e = s_ed[hh] + p.es[s_idx[jl] * HEADS + hh];
                e = (e >= 0.f) ? e : NSLOPE * e;
                s_e[jl * HEADS + hh] = e;
            }
            __syncthreads();
            int hh = t >> 6;
            float m = -1e30f;
            for (int jl = 0; jl < c; ++jl) m = fmaxf(m, s_e[jl * HEADS + hh]);
            float ssum = 0.f, acc = 0.f;
            for (int jl = 0; jl < c; ++jl) {
                float pr = __expf(s_e[jl * HEADS + hh] - m);
                ssum += pr;
                acc = fmaf(pr, p.h[s_idx[jl] * FDIM + t], acc);
            }
            p.x[i * FDIM + t] = fmaxf(acc / ssum + p.b1[t], 0.f);
            __syncthreads();
        }
    }
    gbar(p.bar, p.bar + 1);

    // ---------- P4: h2 = x @ W2 + layer-2 scores ----------
    {
        float4* xs4 = (float4*)sh;     // [G2ROWS*64]
        for (int tb = blockIdx.x; tb < KNODES / G2ROWS; tb += GRID) {
            int r0 = tb * G2ROWS;
            const float4* xg = (const float4*)(p.x + r0 * FDIM);
#pragma unroll
            for (int q = 0; q < (G2ROWS * FDIM / 4) / 256; ++q)
                xs4[q * 256 + t] = xg[q * 256 + t];
            __syncthreads();

            int tl = t & 127, half = t >> 7;
            int rbase = half * 6;
            float acc0[6], acc1[6];
#pragma unroll
            for (int r = 0; r < 6; ++r) { acc0[r] = 0.f; acc1[r] = 0.f; }
            const float2* Wp = (const float2*)p.W2;
            for (int k4 = 0; k4 < FDIM / 4; ++k4) {
                int k = k4 * 4;
                float2 w0 = Wp[(k + 0) * 128 + tl];
                float2 w1 = Wp[(k + 1) * 128 + tl];
                float2 w2 = Wp[(k + 2) * 128 + tl];
                float2 w3 = Wp[(k + 3) * 128 + tl];
#pragma unroll
                for (int r = 0; r < 6; ++r) {
                    float4 xv = xs4[(rbase + r) * 64 + k4];
                    acc0[r] = fmaf(xv.x, w0.x, fmaf(xv.y, w1.x,
                              fmaf(xv.z, w2.x, fmaf(xv.w, w3.x, acc0[r]))));
                    acc1[r] = fmaf(xv.x, w0.y, fmaf(xv.y, w1.y,
                              fmaf(xv.z, w2.y, fmaf(xv.w, w3.y, acc1[r]))));
                }
            }
            int f0 = 2 * tl, f1 = 2 * tl + 1;
            int head = tl >> 5;
            float as0 = p.as2[f0], as1v = p.as2[f1];
            float ad0 = p.ad2[f0], ad1v = p.ad2[f1];
#pragma unroll
            for (int r = 0; r < 6; ++r) {
                int row = r0 + rbase + r;
                *(float2*)&p.h[row * FDIM + f0] = make_float2(acc0[r], acc1[r]);
                float s = fmaf(acc0[r], as0, acc1[r] * as1v);
                float d = fmaf(acc0[r], ad0, acc1[r] * ad1v);
                for (int off = 16; off; off >>= 1) {
                    s += __shfl_down(s, off, 32);
                    d += __shfl_down(d, off, 32);
                }
                if ((t & 31) == 0) {
                    p.es[row * HEADS + head] = s;
                    p.ed[row * HEADS + head] = d;
                }
            }
            __syncthreads();
        }
    }
    gbar(p.bar, p.bar + 1);

    // ---------- P5: layer-2 aggregate + bias + relu + fc (nodes >= MPTS) ----------
    {
        int*   s_idx = (int*)sh;       // [64]
        float* s_e   = sh + 64;        // [256]
        float* s_ed  = sh + 320;       // [4]
        float* s_red = sh + 324;       // [8]
        for (int q = blockIdx.x; q < MPTS; q += GRID) {
            int i = MPTS + q;
            int c = p.cnt[i];
            if (t < c) s_idx[t] = p.idx[i * MAXNBR + t];
            if (t < HEADS) s_ed[t] = p.ed[i * HEADS + t];
            __syncthreads();
            if (t < c * HEADS) {
                int jl = t >> 2, hh = t & 3;
                float e = s_ed[hh] + p.es[s_idx[jl] * HEADS + hh];
                e = (e >= 0.f) ? e : NSLOPE * e;
                s_e[jl * HEADS + hh] = e;
            }
            __syncthreads();
            int hh = t >> 6;
            float m = -1e30f;
            for (int jl = 0; jl < c; ++jl) m = fmaxf(m, s_e[jl * HEADS + hh]);
            float ssum = 0.f, acc = 0.f;
            for (int jl = 0; jl < c; ++jl) {
                float pr = __expf(s_e[jl * HEADS + hh] - m);
                ssum += pr;
                acc = fmaf(pr, p.h[s_idx[jl] * FDIM + t], acc);
            }
            float v = fmaxf(acc / ssum + p.b2[t], 0.f);
            float p0 = v * p.fcw[t * OUTC + 0];
            float p1 = v * p.fcw[t * OUTC + 1];
            for (int off = 32; off; off >>= 1) {
                p0 += __shfl_down(p0, off, 64);
                p1 += __shfl_down(p1, off, 64);
            }
            if ((t & 63) == 0) {
                s_red[(t >> 6) * 2 + 0] = p0;
                s_red[(t >> 6) * 2 + 1] = p1;
            }
            __syncthreads();
            if (t == 0) {
                p.out[q * OUTC + 0] = s_red[0] + s_red[2] + s_red[4] + s_red[6] + p.fcb[0];
                p.out[q * OUTC + 1] = s_red[1] + s_red[3] + s_red[5] + s_red[7] + p.fcb[1];
            }
            __syncthreads();
        }
    }
}

extern "C" void kernel_launch(void* const* d_in, const int* in_sizes, int n_in,
                              void* d_out, int out_size, void* d_ws, size_t ws_size,
                              hipStream_t stream) {
    float* w = (float*)d_ws;
    KP hp;
    hp.pos = (const float*)d_in[0];
    hp.pnm = (const float*)d_in[1];
    hp.W1  = (const float*)d_in[2];
    hp.as1 = (const float*)d_in[3];
    hp.ad1 = (const float*)d_in[4];
    hp.b1  = (const float*)d_in[5];
    hp.W2  = (const float*)d_in[6];
    hp.as2 = (const float*)d_in[7];
    hp.ad2 = (const float*)d_in[8];
    hp.b2  = (const float*)d_in[9];
    hp.fcw = (const float*)d_in[10];
    hp.fcb = (const float*)d_in[11];
    hp.px  = w + OFF_PX;
    hp.py  = w + OFF_PY;
    hp.pz  = w + OFF_PZ;
    hp.sq  = w + OFF_SQ;
    hp.es  = w + OFF_ES;
    hp.ed  = w + OFF_ED;
    hp.x   = w + OFF_A;
    hp.h   = w + OFF_B;
    hp.out = (float*)d_out;
    hp.cnt = (int*)((char*)d_ws + (size_t)4 * OFF_END);
    hp.idx = hp.cnt + KNODES;
    hp.bar = (unsigned*)(hp.idx + KNODES * MAXNBR);

    // Barrier counters sit in d_ws (poisoned 0xAA each call) — zero them.
    hipMemsetAsync(hp.bar, 0, 2 * sizeof(unsigned), stream);
    hipLaunchKernelGGL(k_fused, dim3(GRID), dim3(256), 0, stream, hp);
}

// Round 5
// 143.098 us; speedup vs baseline: 3.5366x; 3.5366x over previous
//
#include <hip/hip_runtime.h>
#include <hip/hip_bf16.h>

// Problem constants
#define NPTS   3000
#define MPTS   3000
#define KNODES 6000
#define HEADS  4
#define FDIM   256      // HEADS*HID
#define OUTC   2
#define R2     0.0025f
#define NSLOPE 0.2f
#define MAXNBR 64
#define NROWS  12       // nbr rows per block: 500 nbr blocks
#define G2ROWS 12       // gemm2 rows per block: 500 blocks, 3 rows/wave

// ---------------- workspace layout (floats) ----------------
#define OFF_ES   0
#define OFF_ED   24000
#define OFF_X    48000        // x (layer-1 out / gemm2 in), 6000*256
#define OFF_H    1584000      // h (transform out), 6000*256
#define OFF_END  3120000      // floats; int region starts at byte 4*OFF_END

__device__ __forceinline__ float4 fma4(float s, float4 w, float4 acc) {
    acc.x = fmaf(s, w.x, acc.x); acc.y = fmaf(s, w.y, acc.y);
    acc.z = fmaf(s, w.z, acc.z); acc.w = fmaf(s, w.w, acc.w);
    return acc;
}

// K1 "fat": blocks [0,500) build neighbor lists; blocks [500,1000) do
// pts + h1 = pts@W1 + layer-1 scores (12 nodes each). The two roles are
// independent: nbr recomputes pts/sq inline from pos/pnm with the exact
// fp32 op sequence (no contraction) so the mask matches the reference
// bit-for-bit where determinism allows.
__global__ void k_fat(const float* __restrict__ pos, const float* __restrict__ pnm,
                      const float* __restrict__ W1, const float* __restrict__ as1,
                      const float* __restrict__ ad1, float* __restrict__ h,
                      float* __restrict__ es, float* __restrict__ ed,
                      int* __restrict__ cnt, int* __restrict__ idx) {
    const int t = threadIdx.x;
    if (blockIdx.x < KNODES / NROWS) {
        // ---- neighbor-list role ----
        __shared__ int s_cnt[NROWS];
        __shared__ int s_idx[NROWS][MAXNBR];
        int i0 = blockIdx.x * NROWS;
        if (t < NROWS) s_cnt[t] = 0;
        __syncthreads();
        // 3000 % NROWS == 0 -> a block's 12 rows never straddle pos/pnm
        const float* base = (i0 < NPTS) ? pos : pnm;
        int ib = (i0 < NPTS) ? i0 : i0 - NPTS;
        float xi[NROWS], yi[NROWS], zi[NROWS], si[NROWS];
#pragma unroll
        for (int r = 0; r < NROWS; ++r) {
            float x = base[ib + r], y = base[NPTS + ib + r], z = base[2 * NPTS + ib + r];
            xi[r] = x; yi[r] = y; zi[r] = z;
            si[r] = __fadd_rn(__fadd_rn(__fmul_rn(x, x), __fmul_rn(y, y)), __fmul_rn(z, z));
        }
        for (int j = t; j < KNODES; j += 256) {
            float xj, yj, zj;
            if (j < NPTS) { xj = pos[j]; yj = pos[NPTS + j]; zj = pos[2 * NPTS + j]; }
            else { int q = j - NPTS; xj = pnm[q]; yj = pnm[MPTS + q]; zj = pnm[2 * MPTS + q]; }
            float sj = __fadd_rn(__fadd_rn(__fmul_rn(xj, xj), __fmul_rn(yj, yj)),
                                 __fmul_rn(zj, zj));
#pragma unroll
            for (int r = 0; r < NROWS; ++r) {
                float dot = __fadd_rn(__fadd_rn(__fmul_rn(xi[r], xj), __fmul_rn(yi[r], yj)),
                                      __fmul_rn(zi[r], zj));
                float d2 = __fsub_rn(__fadd_rn(si[r], sj), __fmul_rn(2.0f, dot));
                if (d2 < R2) {
                    int pp = atomicAdd(&s_cnt[r], 1);
                    if (pp < MAXNBR) s_idx[r][pp] = j;
                }
            }
        }
        __syncthreads();
        if (t < NROWS) cnt[i0 + t] = min(s_cnt[t], MAXNBR);
#pragma unroll
        for (int r = 0; r < NROWS; ++r) {
            int c = min(s_cnt[r], MAXNBR);
            if (t < c) idx[(i0 + r) * MAXNBR + t] = s_idx[r][t];
        }
    } else {
        // ---- pts + h1 + layer-1 scores role ----
        int n0 = (blockIdx.x - KNODES / NROWS) * 12;
        float w1a = W1[t], w1b = W1[FDIM + t], w1c = W1[2 * FDIM + t];
        float asv = as1[t], adv = ad1[t];
        for (int r = 0; r < 12; ++r) {
            int i = n0 + r;
            float x, y, z;
            if (i < NPTS) { x = pos[i]; y = pos[NPTS + i]; z = pos[2 * NPTS + i]; }
            else { int q = i - NPTS; x = pnm[q]; y = pnm[MPTS + q]; z = pnm[2 * MPTS + q]; }
            float hv = fmaf(x, w1a, fmaf(y, w1b, z * w1c));
            h[i * FDIM + t] = hv;
            float s = hv * asv, d = hv * adv;
            for (int off = 32; off; off >>= 1) {
                s += __shfl_down(s, off, 64);
                d += __shfl_down(d, off, 64);
            }
            if ((t & 63) == 0) {
                es[i * HEADS + (t >> 6)] = s;
                ed[i * HEADS + (t >> 6)] = d;
            }
        }
    }
}

// K2: layer-1 sparse softmax-aggregate + bias + relu. One block per node.
__global__ void k_agg(const float* __restrict__ h, const float* __restrict__ es,
                      const float* __restrict__ ed, const int* __restrict__ cnt,
                      const int* __restrict__ idx, const float* __restrict__ bias,
                      float* __restrict__ out) {
    __shared__ int   s_idx[MAXNBR];
    __shared__ float s_e[MAXNBR * HEADS];
    __shared__ float s_ed[HEADS];
    int i = blockIdx.x, t = threadIdx.x;
    int c = cnt[i];
    if (t < c) s_idx[t] = idx[i * MAXNBR + t];
    if (t < HEADS) s_ed[t] = ed[i * HEADS + t];
    __syncthreads();
    if (t < c * HEADS) {
        int jl = t >> 2, hh = t & 3;
        float e = s_ed[hh] + es[s_idx[jl] * HEADS + hh];
        e = (e >= 0.f) ? e : NSLOPE * e;
        s_e[jl * HEADS + hh] = e;
    }
    __syncthreads();
    int hh = t >> 6;
    float m = -1e30f;
    for (int jl = 0; jl < c; ++jl) m = fmaxf(m, s_e[jl * HEADS + hh]);
    float ssum = 0.f, acc = 0.f;
    for (int jl = 0; jl < c; ++jl) {
        float p = __expf(s_e[jl * HEADS + hh] - m);
        ssum += p;
        acc = fmaf(p, h[s_idx[jl] * FDIM + t], acc);
    }
    out[i * FDIM + t] = fmaxf(acc / ssum + bias[t], 0.f);
}

// K3: h2 = x @ W2 + layer-2 scores. 500 blocks x 256 thr; each wave owns
// 3 rows (wave-uniform base via readfirstlane -> x loads become s_load,
// no LDS at all); each lane owns 4 consecutive cols -> W loads are
// global_load_dwordx4, fully coalesced. FMA-issue-bound by design.
__global__ __launch_bounds__(256) void k_gemm2s(const float* __restrict__ x,
        const float* __restrict__ W, const float* __restrict__ as2,
        const float* __restrict__ ad2, float* __restrict__ h,
        float* __restrict__ es, float* __restrict__ ed) {
    const int t = threadIdx.x;
    const int lane = t & 63, wave = t >> 6;
    const int r0 = __builtin_amdgcn_readfirstlane(blockIdx.x * G2ROWS + wave * 3);
    const float4* W4  = (const float4*)W;
    const float4* xr0 = (const float4*)(x + (size_t)(r0 + 0) * FDIM);
    const float4* xr1 = (const float4*)(x + (size_t)(r0 + 1) * FDIM);
    const float4* xr2 = (const float4*)(x + (size_t)(r0 + 2) * FDIM);
    float4 a0 = {0.f, 0.f, 0.f, 0.f}, a1 = a0, a2 = a0;
    for (int k4 = 0; k4 < FDIM / 4; ++k4) {
        float4 xa = xr0[k4], xb = xr1[k4], xc = xr2[k4];   // scalar loads
        float4 w0 = W4[(4 * k4 + 0) * 64 + lane];
        float4 w1 = W4[(4 * k4 + 1) * 64 + lane];
        float4 w2 = W4[(4 * k4 + 2) * 64 + lane];
        float4 w3 = W4[(4 * k4 + 3) * 64 + lane];
        a0 = fma4(xa.x, w0, fma4(xa.y, w1, fma4(xa.z, w2, fma4(xa.w, w3, a0))));
        a1 = fma4(xb.x, w0, fma4(xb.y, w1, fma4(xb.z, w2, fma4(xb.w, w3, a1))));
        a2 = fma4(xc.x, w0, fma4(xc.y, w1, fma4(xc.z, w2, fma4(xc.w, w3, a2))));
    }
    const float4 asv = ((const float4*)as2)[lane];
    const float4 adv = ((const float4*)ad2)[lane];
    const int head = lane >> 4;
    float4 accs[3] = {a0, a1, a2};
#pragma unroll
    for (int r = 0; r < 3; ++r) {
        int row = r0 + r;
        ((float4*)(h + (size_t)row * FDIM))[lane] = accs[r];
        float4 a = accs[r];
        float s = fmaf(a.x, asv.x, fmaf(a.y, asv.y, fmaf(a.z, asv.z, a.w * asv.w)));
        float d = fmaf(a.x, adv.x, fmaf(a.y, adv.y, fmaf(a.z, adv.z, a.w * adv.w)));
        // reduce within each 16-lane group (one head per group)
        for (int off = 8; off; off >>= 1) {
            s += __shfl_down(s, off, 64);
            d += __shfl_down(d, off, 64);
        }
        if ((lane & 15) == 0) {
            es[row * HEADS + head] = s;
            ed[row * HEADS + head] = d;
        }
    }
}

// K4: layer-2 aggregate + bias + relu + fc, output nodes only.
__global__ void k_agg2fc(const float* __restrict__ h, const float* __restrict__ es,
                         const float* __restrict__ ed, const int* __restrict__ cnt,
                         const int* __restrict__ idx, const float* __restrict__ bias,
                         const float* __restrict__ fw, const float* __restrict__ fb,
                         float* __restrict__ out) {
    __shared__ int   s_idx[MAXNBR];
    __shared__ float s_e[MAXNBR * HEADS];
    __shared__ float s_ed[HEADS];
    __shared__ float s_red[8];
    int q = blockIdx.x;
    int i = MPTS + q;
    int t = threadIdx.x;
    int c = cnt[i];
    if (t < c) s_idx[t] = idx[i * MAXNBR + t];
    if (t < HEADS) s_ed[t] = ed[i * HEADS + t];
    __syncthreads();
    if (t < c * HEADS) {
        int jl = t >> 2, hh = t & 3;
        float e = s_ed[hh] + es[s_idx[jl] * HEADS + hh];
        e = (e >= 0.f) ? e : NSLOPE * e;
        s_e[jl * HEADS + hh] = e;
    }
    __syncthreads();
    int hh = t >> 6;
    float m = -1e30f;
    for (int jl = 0; jl < c; ++jl) m = fmaxf(m, s_e[jl * HEADS + hh]);
    float ssum = 0.f, acc = 0.f;
    for (int jl = 0; jl < c; ++jl) {
        float p = __expf(s_e[jl * HEADS + hh] - m);
        ssum += p;
        acc = fmaf(p, h[s_idx[jl] * FDIM + t], acc);
    }
    float v = fmaxf(acc / ssum + bias[t], 0.f);
    float p0 = v * fw[t * OUTC + 0];
    float p1 = v * fw[t * OUTC + 1];
    for (int off = 32; off; off >>= 1) {
        p0 += __shfl_down(p0, off, 64);
        p1 += __shfl_down(p1, off, 64);
    }
    if ((t & 63) == 0) {
        s_red[(t >> 6) * 2 + 0] = p0;
        s_red[(t >> 6) * 2 + 1] = p1;
    }
    __syncthreads();
    if (t == 0) {
        out[q * OUTC + 0] = s_red[0] + s_red[2] + s_red[4] + s_red[6] + fb[0];
        out[q * OUTC + 1] = s_red[1] + s_red[3] + s_red[5] + s_red[7] + fb[1];
    }
}

extern "C" void kernel_launch(void* const* d_in, const int* in_sizes, int n_in,
                              void* d_out, int out_size, void* d_ws, size_t ws_size,
                              hipStream_t stream) {
    const float* pos   = (const float*)d_in[0];
    const float* pnm   = (const float*)d_in[1];
    const float* W1    = (const float*)d_in[2];
    const float* asrc1 = (const float*)d_in[3];
    const float* adst1 = (const float*)d_in[4];
    const float* b1    = (const float*)d_in[5];
    const float* W2    = (const float*)d_in[6];
    const float* asrc2 = (const float*)d_in[7];
    const float* adst2 = (const float*)d_in[8];
    const float* b2    = (const float*)d_in[9];
    const float* fcw   = (const float*)d_in[10];
    const float* fcb   = (const float*)d_in[11];
    float* out = (float*)d_out;

    float* w   = (float*)d_ws;
    float* es  = w + OFF_ES;
    float* ed  = w + OFF_ED;
    float* x   = w + OFF_X;
    float* h   = w + OFF_H;
    int* nbr_cnt = (int*)((char*)d_ws + (size_t)4 * OFF_END);
    int* nbr_idx = nbr_cnt + KNODES;

    // K1: nbr (500 blocks) + pts/h1/scores (500 blocks)
    k_fat<<<1000, 256, 0, stream>>>(pos, pnm, W1, asrc1, adst1, h, es, ed,
                                    nbr_cnt, nbr_idx);
    // K2: layer-1 aggregate -> x
    k_agg<<<KNODES, FDIM, 0, stream>>>(h, es, ed, nbr_cnt, nbr_idx, b1, x);
    // K3: h2 = x@W2 + layer-2 scores
    k_gemm2s<<<KNODES / G2ROWS, 256, 0, stream>>>(x, W2, asrc2, adst2, h, es, ed);
    // K4: layer-2 aggregate + fc
    k_agg2fc<<<MPTS, FDIM, 0, stream>>>(h, es, ed, nbr_cnt, nbr_idx, b2, fcw, fcb, out);
}